// Round 6
// baseline (221.618 us; speedup 1.0000x reference)
//
#include <hip/hip_runtime.h>
#include <hip/hip_bf16.h>

// Problem dims (fixed by reference): B=2,S=1024 -> T=2048 tokens
#define T_TOK 2048
#define DIM   2048   // D
#define FFN   1024   // F
#define NE    8      // experts
// top_k = 2 hardcoded

typedef __attribute__((ext_vector_type(8))) short bf16x8;
typedef __attribute__((ext_vector_type(8))) unsigned short u16x8;
typedef __attribute__((ext_vector_type(4))) float f32x4;

__device__ __forceinline__ unsigned short f2bf(float f) {
  __hip_bfloat16 h = __float2bfloat16(f);
  return __builtin_bit_cast(unsigned short, h);
}

__device__ __forceinline__ void gload_lds16(const unsigned short* g, unsigned short* l) {
  __builtin_amdgcn_global_load_lds(
      (const __attribute__((address_space(1))) void*)g,
      (__attribute__((address_space(3))) void*)l, 16, 0, 0);
}

__device__ __forceinline__ u16x8 cvt8(float4 a, float4 b) {
  u16x8 o;
  o[0] = f2bf(a.x); o[1] = f2bf(a.y); o[2] = f2bf(a.z); o[3] = f2bf(a.w);
  o[4] = f2bf(b.x); o[5] = f2bf(b.y); o[6] = f2bf(b.z); o[7] = f2bf(b.w);
  return o;
}

// ---------------- fp32 -> bf16: branch-free, 4 groups x 8 floats per thread ----------------
// grid must satisfy: gridDim.x * 256 * 4 * 8 == n_floats (all sizes are pow2 here)
__global__ __launch_bounds__(256) void cvt4(const float* __restrict__ src,
                                            unsigned short* __restrict__ dst) {
  const int tid = blockIdx.x * 256 + threadIdx.x;
  const int nthreads = gridDim.x * 256;
  const float4* s = reinterpret_cast<const float4*>(src);
  u16x8* d = reinterpret_cast<u16x8*>(dst);
#pragma unroll
  for (int g = 0; g < 4; ++g) {
    long grp = (long)g * nthreads + tid;
    float4 a = s[grp * 2];
    float4 b = s[grp * 2 + 1];
    d[grp] = cvt8(a, b);
  }
}

// ---------------- router: logits + top2 + softmax gates ----------------
__global__ __launch_bounds__(256) void router_topk(
    const float* __restrict__ x, const float* __restrict__ wr,
    int* __restrict__ top_i, float* __restrict__ top_g) {
  int t = blockIdx.x * 4 + (threadIdx.x >> 6);
  int lane = threadIdx.x & 63;
  const float4* xr = reinterpret_cast<const float4*>(x) + (size_t)t * (DIM / 4);
  const float4* wrv = reinterpret_cast<const float4*>(wr);
  float acc[NE];
#pragma unroll
  for (int e = 0; e < NE; ++e) acc[e] = 0.f;
#pragma unroll
  for (int it = 0; it < DIM / 4 / 64; ++it) {
    int d4 = it * 64 + lane;
    float4 xv = xr[d4];
#pragma unroll
    for (int e = 0; e < NE; ++e) {
      float4 wv = wrv[e * (DIM / 4) + d4];
      acc[e] += xv.x * wv.x + xv.y * wv.y + xv.z * wv.z + xv.w * wv.w;
    }
  }
#pragma unroll
  for (int off = 32; off > 0; off >>= 1) {
#pragma unroll
    for (int e = 0; e < NE; ++e) acc[e] += __shfl_xor(acc[e], off, 64);
  }
  if (lane == 0) {
    int i0 = 0; float m0 = acc[0];
#pragma unroll
    for (int e = 1; e < NE; ++e) if (acc[e] > m0) { m0 = acc[e]; i0 = e; }
    int i1 = -1; float m1 = -3.4e38f;
#pragma unroll
    for (int e = 0; e < NE; ++e) if (e != i0 && acc[e] > m1) { m1 = acc[e]; i1 = e; }
    float tv = expf(m1 - m0);
    float den = 1.f + tv;
    top_i[t * 2 + 0] = i0; top_i[t * 2 + 1] = i1;
    top_g[t * 2 + 0] = 1.f / den; top_g[t * 2 + 1] = tv / den;
  }
}

// ---------------- count per expert + exclusive prefix offsets ----------------
__global__ void count_offsets(const int* __restrict__ top_i,
                              int* __restrict__ offs, int* __restrict__ cursor) {
  __shared__ int cnt[NE];
  if (threadIdx.x < NE) cnt[threadIdx.x] = 0;
  __syncthreads();
  for (int i = threadIdx.x; i < T_TOK * 2; i += blockDim.x) atomicAdd(&cnt[top_i[i]], 1);
  __syncthreads();
  if (threadIdx.x == 0) {
    int s = 0;
    for (int e = 0; e < NE; ++e) { offs[e] = s; cursor[e] = s; s += cnt[e]; }
    offs[NE] = s;
  }
}

// ---------------- scatter tokens into compact per-expert lists ----------------
__global__ void scatter_tokens(const int* __restrict__ top_i, const float* __restrict__ top_g,
                               int* __restrict__ cursor, int* __restrict__ tok_list,
                               float* __restrict__ gate_lst, int* __restrict__ slot_lst) {
  int t = blockIdx.x * blockDim.x + threadIdx.x;
  if (t >= T_TOK) return;
#pragma unroll
  for (int s = 0; s < 2; ++s) {
    int e = top_i[t * 2 + s];
    int p = atomicAdd(&cursor[e], 1);
    tok_list[p] = t;
    gate_lst[p] = top_g[t * 2 + s];
    slot_lst[p] = s;
  }
}

// ============ fused gate+up grouped GEMM: BM=64, BN=64, BK=64 (R5-frozen) ============
// + fused wd fp32->bf16 conversion in extra x-blocks (overlaps latency-bound GEMM).
// LDS rows 128B = 8 x 16B chunks, swizzle c ^= (row&7).
__global__ __launch_bounds__(256, 4) void gateup_gemm(
    const unsigned short* __restrict__ xb, const unsigned short* __restrict__ wgb,
    const unsigned short* __restrict__ wub, const int* __restrict__ tok_list,
    const int* __restrict__ offs, unsigned short* __restrict__ hbuf,
    const float* __restrict__ wd_f32, unsigned short* __restrict__ wdb) {
  if (blockIdx.x >= FFN / 64) {
    // ---- wd conversion blocks: 4 x 32 x 8 = 1024 blocks, 8 groups/thread ----
    int cb = (blockIdx.x - FFN / 64) + 4 * (blockIdx.y + 32 * blockIdx.z);
    int t = cb * 256 + threadIdx.x;              // 0..262143
    const float4* s = reinterpret_cast<const float4*>(wd_f32);
    u16x8* d = reinterpret_cast<u16x8*>(wdb);
#pragma unroll
    for (int g = 0; g < 8; ++g) {
      long grp = (long)g * 262144 + t;           // 2,097,152 groups total
      float4 a = s[grp * 2];
      float4 b = s[grp * 2 + 1];
      d[grp] = cvt8(a, b);
    }
    return;
  }
  const int e = blockIdx.z;
  const int row0 = offs[e];
  const int n_e = offs[e + 1] - row0;
  const int mt = blockIdx.y;
  if (mt * 64 >= n_e) return;
  const int nt = blockIdx.x;    // F tile of 64

  __shared__ unsigned short As[64 * 64];   // 8KB
  __shared__ unsigned short Bg[64 * 64];   // 8KB
  __shared__ unsigned short Bu[64 * 64];   // 8KB

  const int tid = threadIdx.x;
  const int wid = tid >> 6;
  const int lane = tid & 63;

  const int gchunk = (((lane & 7) ^ ((lane >> 3) & 7)) << 3);

  const unsigned short* gA[2];
  int lAoff[2];
#pragma unroll
  for (int p = 0; p < 2; ++p) {
    int rt = wid * 16 + p * 8 + (lane >> 3);
    int ar = mt * 64 + rt; if (ar >= n_e) ar = n_e - 1;
    gA[p] = xb + (size_t)tok_list[row0 + ar] * DIM + gchunk;
    lAoff[p] = (wid * 16 + p * 8) * 64;
  }
  const size_t wbase = (size_t)e * FFN * DIM + (size_t)(nt * 64) * DIM;
  const unsigned short* gG[2];
  const unsigned short* gU[2];
  int lBoff[2];
#pragma unroll
  for (int p = 0; p < 2; ++p) {
    int rt = wid * 16 + p * 8 + (lane >> 3);
    gG[p] = wgb + wbase + (size_t)rt * DIM + gchunk;
    gU[p] = wub + wbase + (size_t)rt * DIM + gchunk;
    lBoff[p] = (wid * 16 + p * 8) * 64;
  }

  f32x4 accg[2][2];
  f32x4 accu[2][2];
#pragma unroll
  for (int i = 0; i < 2; ++i)
#pragma unroll
    for (int j = 0; j < 2; ++j) {
      accg[i][j] = (f32x4){0.f, 0.f, 0.f, 0.f};
      accu[i][j] = (f32x4){0.f, 0.f, 0.f, 0.f};
    }

  const int warow = (wid >> 1) * 32;   // 2x2 wave grid, 32x32 per wave
  const int wacol = (wid & 1) * 32;
  const int frow = lane & 15;
  const int eo0 = ((((lane >> 4)) ^ (lane & 7)) << 3);
  const int eo1 = (((4 + (lane >> 4)) ^ (lane & 7)) << 3);

  for (int k0 = 0; k0 < DIM; k0 += 64) {
#pragma unroll
    for (int p = 0; p < 2; ++p) {
      gload_lds16(gA[p] + k0, &As[lAoff[p]]);
      gload_lds16(gG[p] + k0, &Bg[lBoff[p]]);
      gload_lds16(gU[p] + k0, &Bu[lBoff[p]]);
    }
    __syncthreads();
#pragma unroll
    for (int kk = 0; kk < 2; ++kk) {
      const int eo = kk ? eo1 : eo0;
      bf16x8 af[2], bg[2], bu[2];
#pragma unroll
      for (int i = 0; i < 2; ++i)
        af[i] = *reinterpret_cast<const bf16x8*>(&As[(warow + i * 16 + frow) * 64 + eo]);
#pragma unroll
      for (int j = 0; j < 2; ++j) {
        bg[j] = *reinterpret_cast<const bf16x8*>(&Bg[(wacol + j * 16 + frow) * 64 + eo]);
        bu[j] = *reinterpret_cast<const bf16x8*>(&Bu[(wacol + j * 16 + frow) * 64 + eo]);
      }
#pragma unroll
      for (int i = 0; i < 2; ++i)
#pragma unroll
        for (int j = 0; j < 2; ++j) {
          accg[i][j] = __builtin_amdgcn_mfma_f32_16x16x32_bf16(af[i], bg[j], accg[i][j], 0, 0, 0);
          accu[i][j] = __builtin_amdgcn_mfma_f32_16x16x32_bf16(af[i], bu[j], accu[i][j], 0, 0, 0);
        }
    }
    __syncthreads();
  }

  // epilogue: h = silu(g)*u -> bf16
#pragma unroll
  for (int i = 0; i < 2; ++i) {
#pragma unroll
    for (int jj = 0; jj < 4; ++jj) {
      int r = mt * 64 + warow + i * 16 + (lane >> 4) * 4 + jj;
      if (r < n_e) {
#pragma unroll
        for (int j = 0; j < 2; ++j) {
          float g = accg[i][j][jj];
          float u = accu[i][j][jj];
          float h = (g / (1.f + __expf(-g))) * u;
          int f = nt * 64 + wacol + j * 16 + (lane & 15);
          hbuf[(size_t)(row0 + r) * FFN + f] = f2bf(h);
        }
      }
    }
  }
}

// ============ grouped down GEMM: BM=64, BN=128, BK=64 (R5-frozen) ============
__global__ __launch_bounds__(256, 4) void down_gemm(
    const unsigned short* __restrict__ hbuf, const unsigned short* __restrict__ wdb,
    const int* __restrict__ tok_list, const float* __restrict__ gate_lst,
    const int* __restrict__ slot_lst, const int* __restrict__ offs,
    float* __restrict__ yslots) {
  const int e = blockIdx.z;
  const int row0 = offs[e];
  const int n_e = offs[e + 1] - row0;
  const int mt = blockIdx.y;
  if (mt * 64 >= n_e) return;
  const int nt = blockIdx.x;  // D tile

  __shared__ unsigned short As[64 * 64];    // 8KB
  __shared__ unsigned short Bs[128 * 64];   // 16KB

  const int tid = threadIdx.x;
  const int wid = tid >> 6;
  const int lane = tid & 63;

  const int gchunk = (((lane & 7) ^ ((lane >> 3) & 7)) << 3);

  const unsigned short* gA[2];
  int lAoff[2];
#pragma unroll
  for (int p = 0; p < 2; ++p) {
    int rt = wid * 16 + p * 8 + (lane >> 3);
    int ar = mt * 64 + rt; if (ar >= n_e) ar = n_e - 1;
    gA[p] = hbuf + (size_t)(row0 + ar) * FFN + gchunk;
    lAoff[p] = (wid * 16 + p * 8) * 64;
  }
  const unsigned short* gB[4];
  int lBoff[4];
#pragma unroll
  for (int p = 0; p < 4; ++p) {
    int rt = wid * 32 + p * 8 + (lane >> 3);
    gB[p] = wdb + ((size_t)e * DIM + nt * 128 + rt) * FFN + gchunk;
    lBoff[p] = (wid * 32 + p * 8) * 64;
  }

  f32x4 acc[2][4];
#pragma unroll
  for (int i = 0; i < 2; ++i)
#pragma unroll
    for (int j = 0; j < 4; ++j) acc[i][j] = (f32x4){0.f, 0.f, 0.f, 0.f};

  const int warow = (wid >> 1) * 32;
  const int wacol = (wid & 1) * 64;
  const int frow = lane & 15;
  const int eo0 = ((((lane >> 4)) ^ (lane & 7)) << 3);
  const int eo1 = (((4 + (lane >> 4)) ^ (lane & 7)) << 3);

  for (int k0 = 0; k0 < FFN; k0 += 64) {
#pragma unroll
    for (int p = 0; p < 2; ++p) gload_lds16(gA[p] + k0, &As[lAoff[p]]);
#pragma unroll
    for (int p = 0; p < 4; ++p) gload_lds16(gB[p] + k0, &Bs[lBoff[p]]);
    __syncthreads();
#pragma unroll
    for (int kk = 0; kk < 2; ++kk) {
      const int eo = kk ? eo1 : eo0;
      bf16x8 af[2], bf[4];
#pragma unroll
      for (int i = 0; i < 2; ++i)
        af[i] = *reinterpret_cast<const bf16x8*>(&As[(warow + i * 16 + frow) * 64 + eo]);
#pragma unroll
      for (int j = 0; j < 4; ++j)
        bf[j] = *reinterpret_cast<const bf16x8*>(&Bs[(wacol + j * 16 + frow) * 64 + eo]);
#pragma unroll
      for (int i = 0; i < 2; ++i)
#pragma unroll
        for (int j = 0; j < 4; ++j)
          acc[i][j] = __builtin_amdgcn_mfma_f32_16x16x32_bf16(af[i], bf[j], acc[i][j], 0, 0, 0);
    }
    __syncthreads();
  }

#pragma unroll
  for (int i = 0; i < 2; ++i) {
#pragma unroll
    for (int jj = 0; jj < 4; ++jj) {
      int r = mt * 64 + warow + i * 16 + (lane >> 4) * 4 + jj;
      if (r < n_e) {
        int tk = tok_list[row0 + r];
        float gt = gate_lst[row0 + r];
        int sl = slot_lst[row0 + r];
        float* yrow = yslots + ((size_t)sl * T_TOK + tk) * DIM;
#pragma unroll
        for (int j = 0; j < 4; ++j) {
          int d = nt * 128 + wacol + j * 16 + (lane & 15);
          yrow[d] = gt * acc[i][j][jj];
        }
      }
    }
  }
}

// ---------------- combine slots ----------------
__global__ void combine(const float* __restrict__ y, float* __restrict__ out) {
  int i = blockIdx.x * blockDim.x + threadIdx.x;
  int stride = gridDim.x * blockDim.x;
  const float4* y0 = reinterpret_cast<const float4*>(y);
  const float4* y1 = reinterpret_cast<const float4*>(y + (size_t)T_TOK * DIM);
  float4* o = reinterpret_cast<float4*>(out);
  for (; i < T_TOK * DIM / 4; i += stride) {
    float4 a = y0[i], b = y1[i];
    float4 r;
    r.x = a.x + b.x; r.y = a.y + b.y; r.z = a.z + b.z; r.w = a.w + b.w;
    o[i] = r;
  }
}

extern "C" void kernel_launch(void* const* d_in, const int* in_sizes, int n_in,
                              void* d_out, int out_size, void* d_ws, size_t ws_size,
                              hipStream_t stream) {
  const float* x = (const float*)d_in[0];
  const float* wr = (const float*)d_in[1];
  const float* wg = (const float*)d_in[2];
  const float* wu = (const float*)d_in[3];
  const float* wd = (const float*)d_in[4];
  float* out = (float*)d_out;

  char* ws = (char*)d_ws;
  size_t off = 0;
  auto alloc = [&](size_t bytes) {
    char* p = ws + off;
    off += (bytes + 255) & ~(size_t)255;
    return p;
  };
  unsigned short* xb   = (unsigned short*)alloc((size_t)T_TOK * DIM * 2);
  unsigned short* wgb  = (unsigned short*)alloc((size_t)NE * FFN * DIM * 2);
  unsigned short* wub  = (unsigned short*)alloc((size_t)NE * FFN * DIM * 2);
  unsigned short* wdb  = (unsigned short*)alloc((size_t)NE * DIM * FFN * 2);
  unsigned short* hbuf = (unsigned short*)alloc((size_t)T_TOK * 2 * FFN * 2);
  float* yslots        = (float*)alloc((size_t)2 * T_TOK * DIM * 4);
  int* top_i     = (int*)alloc(T_TOK * 2 * 4);
  float* top_g   = (float*)alloc(T_TOK * 2 * 4);
  int* tok_list  = (int*)alloc(T_TOK * 2 * 4);
  float* gate_lst = (float*)alloc(T_TOK * 2 * 4);
  int* slot_lst  = (int*)alloc(T_TOK * 2 * 4);
  int* offs      = (int*)alloc(64);
  int* cursor    = (int*)alloc(64);
  if (off > ws_size) return;

  // branch-free cvt: grid*256*32 floats per launch
  cvt4<<<512, 256, 0, stream>>>(x, xb);        // 4.19M floats
  cvt4<<<2048, 256, 0, stream>>>(wg, wgb);     // 16.8M floats
  cvt4<<<2048, 256, 0, stream>>>(wu, wub);     // 16.8M floats
  router_topk<<<T_TOK / 4, 256, 0, stream>>>(x, wr, top_i, top_g);
  count_offsets<<<1, 256, 0, stream>>>(top_i, offs, cursor);
  scatter_tokens<<<(T_TOK + 255) / 256, 256, 0, stream>>>(top_i, top_g, cursor, tok_list,
                                                          gate_lst, slot_lst);
  // gateup + fused wd conversion (extra 4 x-slices = 1024 cvt blocks)
  gateup_gemm<<<dim3(FFN / 64 + 4, 32, NE), 256, 0, stream>>>(xb, wgb, wub, tok_list, offs,
                                                              hbuf, wd, wdb);
  down_gemm<<<dim3(DIM / 128, 32, NE), 256, 0, stream>>>(hbuf, wdb, tok_list, gate_lst,
                                                         slot_lst, offs, yslots);
  combine<<<2048, 256, 0, stream>>>(yslots, out);
}

// Round 7
// 199.014 us; speedup vs baseline: 1.1136x; 1.1136x over previous
//
#include <hip/hip_runtime.h>
#include <hip/hip_bf16.h>

// Problem dims (fixed by reference): B=2,S=1024 -> T=2048 tokens
#define T_TOK 2048
#define DIM   2048   // D
#define FFN   1024   // F
#define NE    8      // experts
// top_k = 2 hardcoded

typedef __attribute__((ext_vector_type(8))) short bf16x8;
typedef __attribute__((ext_vector_type(8))) unsigned short u16x8;
typedef __attribute__((ext_vector_type(4))) float f32x4;

__device__ __forceinline__ unsigned short f2bf(float f) {
  __hip_bfloat16 h = __float2bfloat16(f);
  return __builtin_bit_cast(unsigned short, h);
}

__device__ __forceinline__ void gload_lds16(const unsigned short* g, unsigned short* l) {
  __builtin_amdgcn_global_load_lds(
      (const __attribute__((address_space(1))) void*)g,
      (__attribute__((address_space(3))) void*)l, 16, 0, 0);
}

__device__ __forceinline__ u16x8 cvt8(float4 a, float4 b) {
  u16x8 o;
  o[0] = f2bf(a.x); o[1] = f2bf(a.y); o[2] = f2bf(a.z); o[3] = f2bf(a.w);
  o[4] = f2bf(b.x); o[5] = f2bf(b.y); o[6] = f2bf(b.z); o[7] = f2bf(b.w);
  return o;
}

// ---------------- fp32 -> bf16, all 4 tensors, one kernel ----------------
// Block-uniform segment decode (scalar branch); 4 groups x 8 floats per thread,
// fully unrolled -> 8 independent dwordx4 loads in flight.
// Segments (blocks of 1024 groups): x=512, wg=2048, wu=2048, wd=2048 -> 6656 blocks.
__global__ __launch_bounds__(256) void cvt_bulk(
    const float* __restrict__ x, const float* __restrict__ wg,
    const float* __restrict__ wu, const float* __restrict__ wd,
    unsigned short* __restrict__ xb, unsigned short* __restrict__ wgb,
    unsigned short* __restrict__ wub, unsigned short* __restrict__ wdb) {
  const int b = blockIdx.x;
  const float* src;
  unsigned short* dst;
  long base;
  if (b < 512)       { src = x;  dst = xb;  base = (long)b * 1024; }
  else if (b < 2560) { src = wg; dst = wgb; base = (long)(b - 512) * 1024; }
  else if (b < 4608) { src = wu; dst = wub; base = (long)(b - 2560) * 1024; }
  else               { src = wd; dst = wdb; base = (long)(b - 4608) * 1024; }
  const float4* s = reinterpret_cast<const float4*>(src);
  u16x8* d = reinterpret_cast<u16x8*>(dst);
#pragma unroll
  for (int g = 0; g < 4; ++g) {
    long grp = base + g * 256 + threadIdx.x;
    float4 a = s[grp * 2];
    float4 bq = s[grp * 2 + 1];
    d[grp] = cvt8(a, bq);
  }
}

// ---------------- router: logits + top2 + softmax gates ----------------
__global__ __launch_bounds__(256) void router_topk(
    const float* __restrict__ x, const float* __restrict__ wr,
    int* __restrict__ top_i, float* __restrict__ top_g) {
  int t = blockIdx.x * 4 + (threadIdx.x >> 6);
  int lane = threadIdx.x & 63;
  const float4* xr = reinterpret_cast<const float4*>(x) + (size_t)t * (DIM / 4);
  const float4* wrv = reinterpret_cast<const float4*>(wr);
  float acc[NE];
#pragma unroll
  for (int e = 0; e < NE; ++e) acc[e] = 0.f;
#pragma unroll
  for (int it = 0; it < DIM / 4 / 64; ++it) {
    int d4 = it * 64 + lane;
    float4 xv = xr[d4];
#pragma unroll
    for (int e = 0; e < NE; ++e) {
      float4 wv = wrv[e * (DIM / 4) + d4];
      acc[e] += xv.x * wv.x + xv.y * wv.y + xv.z * wv.z + xv.w * wv.w;
    }
  }
#pragma unroll
  for (int off = 32; off > 0; off >>= 1) {
#pragma unroll
    for (int e = 0; e < NE; ++e) acc[e] += __shfl_xor(acc[e], off, 64);
  }
  if (lane == 0) {
    int i0 = 0; float m0 = acc[0];
#pragma unroll
    for (int e = 1; e < NE; ++e) if (acc[e] > m0) { m0 = acc[e]; i0 = e; }
    int i1 = -1; float m1 = -3.4e38f;
#pragma unroll
    for (int e = 0; e < NE; ++e) if (e != i0 && acc[e] > m1) { m1 = acc[e]; i1 = e; }
    float tv = expf(m1 - m0);
    float den = 1.f + tv;
    top_i[t * 2 + 0] = i0; top_i[t * 2 + 1] = i1;
    top_g[t * 2 + 0] = 1.f / den; top_g[t * 2 + 1] = tv / den;
  }
}

// ---------------- count per expert + exclusive prefix offsets ----------------
__global__ void count_offsets(const int* __restrict__ top_i,
                              int* __restrict__ offs, int* __restrict__ cursor) {
  __shared__ int cnt[NE];
  if (threadIdx.x < NE) cnt[threadIdx.x] = 0;
  __syncthreads();
  for (int i = threadIdx.x; i < T_TOK * 2; i += blockDim.x) atomicAdd(&cnt[top_i[i]], 1);
  __syncthreads();
  if (threadIdx.x == 0) {
    int s = 0;
    for (int e = 0; e < NE; ++e) { offs[e] = s; cursor[e] = s; s += cnt[e]; }
    offs[NE] = s;
  }
}

// ---------------- scatter tokens into compact per-expert lists ----------------
__global__ void scatter_tokens(const int* __restrict__ top_i, const float* __restrict__ top_g,
                               int* __restrict__ cursor, int* __restrict__ tok_list,
                               float* __restrict__ gate_lst, int* __restrict__ slot_lst) {
  int t = blockIdx.x * blockDim.x + threadIdx.x;
  if (t >= T_TOK) return;
#pragma unroll
  for (int s = 0; s < 2; ++s) {
    int e = top_i[t * 2 + s];
    int p = atomicAdd(&cursor[e], 1);
    tok_list[p] = t;
    gate_lst[p] = top_g[t * 2 + s];
    slot_lst[p] = s;
  }
}

// ============ fused gate+up grouped GEMM: BM=64, BN=64, BK=64 (R5-frozen) ============
// LDS rows 128B = 8 x 16B chunks, swizzle c ^= (row&7).
__global__ __launch_bounds__(256, 4) void gateup_gemm(
    const unsigned short* __restrict__ xb, const unsigned short* __restrict__ wgb,
    const unsigned short* __restrict__ wub, const int* __restrict__ tok_list,
    const int* __restrict__ offs, unsigned short* __restrict__ hbuf) {
  const int e = blockIdx.z;
  const int row0 = offs[e];
  const int n_e = offs[e + 1] - row0;
  const int mt = blockIdx.y;
  if (mt * 64 >= n_e) return;
  const int nt = blockIdx.x;    // F tile of 64

  __shared__ unsigned short As[64 * 64];   // 8KB
  __shared__ unsigned short Bg[64 * 64];   // 8KB
  __shared__ unsigned short Bu[64 * 64];   // 8KB

  const int tid = threadIdx.x;
  const int wid = tid >> 6;
  const int lane = tid & 63;

  const int gchunk = (((lane & 7) ^ ((lane >> 3) & 7)) << 3);

  const unsigned short* gA[2];
  int lAoff[2];
#pragma unroll
  for (int p = 0; p < 2; ++p) {
    int rt = wid * 16 + p * 8 + (lane >> 3);
    int ar = mt * 64 + rt; if (ar >= n_e) ar = n_e - 1;
    gA[p] = xb + (size_t)tok_list[row0 + ar] * DIM + gchunk;
    lAoff[p] = (wid * 16 + p * 8) * 64;
  }
  const size_t wbase = (size_t)e * FFN * DIM + (size_t)(nt * 64) * DIM;
  const unsigned short* gG[2];
  const unsigned short* gU[2];
  int lBoff[2];
#pragma unroll
  for (int p = 0; p < 2; ++p) {
    int rt = wid * 16 + p * 8 + (lane >> 3);
    gG[p] = wgb + wbase + (size_t)rt * DIM + gchunk;
    gU[p] = wub + wbase + (size_t)rt * DIM + gchunk;
    lBoff[p] = (wid * 16 + p * 8) * 64;
  }

  f32x4 accg[2][2];
  f32x4 accu[2][2];
#pragma unroll
  for (int i = 0; i < 2; ++i)
#pragma unroll
    for (int j = 0; j < 2; ++j) {
      accg[i][j] = (f32x4){0.f, 0.f, 0.f, 0.f};
      accu[i][j] = (f32x4){0.f, 0.f, 0.f, 0.f};
    }

  const int warow = (wid >> 1) * 32;   // 2x2 wave grid, 32x32 per wave
  const int wacol = (wid & 1) * 32;
  const int frow = lane & 15;
  const int eo0 = ((((lane >> 4)) ^ (lane & 7)) << 3);
  const int eo1 = (((4 + (lane >> 4)) ^ (lane & 7)) << 3);

  for (int k0 = 0; k0 < DIM; k0 += 64) {
#pragma unroll
    for (int p = 0; p < 2; ++p) {
      gload_lds16(gA[p] + k0, &As[lAoff[p]]);
      gload_lds16(gG[p] + k0, &Bg[lBoff[p]]);
      gload_lds16(gU[p] + k0, &Bu[lBoff[p]]);
    }
    __syncthreads();
#pragma unroll
    for (int kk = 0; kk < 2; ++kk) {
      const int eo = kk ? eo1 : eo0;
      bf16x8 af[2], bg[2], bu[2];
#pragma unroll
      for (int i = 0; i < 2; ++i)
        af[i] = *reinterpret_cast<const bf16x8*>(&As[(warow + i * 16 + frow) * 64 + eo]);
#pragma unroll
      for (int j = 0; j < 2; ++j) {
        bg[j] = *reinterpret_cast<const bf16x8*>(&Bg[(wacol + j * 16 + frow) * 64 + eo]);
        bu[j] = *reinterpret_cast<const bf16x8*>(&Bu[(wacol + j * 16 + frow) * 64 + eo]);
      }
#pragma unroll
      for (int i = 0; i < 2; ++i)
#pragma unroll
        for (int j = 0; j < 2; ++j) {
          accg[i][j] = __builtin_amdgcn_mfma_f32_16x16x32_bf16(af[i], bg[j], accg[i][j], 0, 0, 0);
          accu[i][j] = __builtin_amdgcn_mfma_f32_16x16x32_bf16(af[i], bu[j], accu[i][j], 0, 0, 0);
        }
    }
    __syncthreads();
  }

  // epilogue: h = silu(g)*u -> bf16
#pragma unroll
  for (int i = 0; i < 2; ++i) {
#pragma unroll
    for (int jj = 0; jj < 4; ++jj) {
      int r = mt * 64 + warow + i * 16 + (lane >> 4) * 4 + jj;
      if (r < n_e) {
#pragma unroll
        for (int j = 0; j < 2; ++j) {
          float g = accg[i][j][jj];
          float u = accu[i][j][jj];
          float h = (g / (1.f + __expf(-g))) * u;
          int f = nt * 64 + wacol + j * 16 + (lane & 15);
          hbuf[(size_t)(row0 + r) * FFN + f] = f2bf(h);
        }
      }
    }
  }
}

// ============ grouped down GEMM: BM=64, BN=128, BK=64 (R5-frozen) ============
__global__ __launch_bounds__(256, 4) void down_gemm(
    const unsigned short* __restrict__ hbuf, const unsigned short* __restrict__ wdb,
    const int* __restrict__ tok_list, const float* __restrict__ gate_lst,
    const int* __restrict__ slot_lst, const int* __restrict__ offs,
    float* __restrict__ yslots) {
  const int e = blockIdx.z;
  const int row0 = offs[e];
  const int n_e = offs[e + 1] - row0;
  const int mt = blockIdx.y;
  if (mt * 64 >= n_e) return;
  const int nt = blockIdx.x;  // D tile

  __shared__ unsigned short As[64 * 64];    // 8KB
  __shared__ unsigned short Bs[128 * 64];   // 16KB

  const int tid = threadIdx.x;
  const int wid = tid >> 6;
  const int lane = tid & 63;

  const int gchunk = (((lane & 7) ^ ((lane >> 3) & 7)) << 3);

  const unsigned short* gA[2];
  int lAoff[2];
#pragma unroll
  for (int p = 0; p < 2; ++p) {
    int rt = wid * 16 + p * 8 + (lane >> 3);
    int ar = mt * 64 + rt; if (ar >= n_e) ar = n_e - 1;
    gA[p] = hbuf + (size_t)(row0 + ar) * FFN + gchunk;
    lAoff[p] = (wid * 16 + p * 8) * 64;
  }
  const unsigned short* gB[4];
  int lBoff[4];
#pragma unroll
  for (int p = 0; p < 4; ++p) {
    int rt = wid * 32 + p * 8 + (lane >> 3);
    gB[p] = wdb + ((size_t)e * DIM + nt * 128 + rt) * FFN + gchunk;
    lBoff[p] = (wid * 32 + p * 8) * 64;
  }

  f32x4 acc[2][4];
#pragma unroll
  for (int i = 0; i < 2; ++i)
#pragma unroll
    for (int j = 0; j < 4; ++j) acc[i][j] = (f32x4){0.f, 0.f, 0.f, 0.f};

  const int warow = (wid >> 1) * 32;
  const int wacol = (wid & 1) * 64;
  const int frow = lane & 15;
  const int eo0 = ((((lane >> 4)) ^ (lane & 7)) << 3);
  const int eo1 = (((4 + (lane >> 4)) ^ (lane & 7)) << 3);

  for (int k0 = 0; k0 < FFN; k0 += 64) {
#pragma unroll
    for (int p = 0; p < 2; ++p) gload_lds16(gA[p] + k0, &As[lAoff[p]]);
#pragma unroll
    for (int p = 0; p < 4; ++p) gload_lds16(gB[p] + k0, &Bs[lBoff[p]]);
    __syncthreads();
#pragma unroll
    for (int kk = 0; kk < 2; ++kk) {
      const int eo = kk ? eo1 : eo0;
      bf16x8 af[2], bf[4];
#pragma unroll
      for (int i = 0; i < 2; ++i)
        af[i] = *reinterpret_cast<const bf16x8*>(&As[(warow + i * 16 + frow) * 64 + eo]);
#pragma unroll
      for (int j = 0; j < 4; ++j)
        bf[j] = *reinterpret_cast<const bf16x8*>(&Bs[(wacol + j * 16 + frow) * 64 + eo]);
#pragma unroll
      for (int i = 0; i < 2; ++i)
#pragma unroll
        for (int j = 0; j < 4; ++j)
          acc[i][j] = __builtin_amdgcn_mfma_f32_16x16x32_bf16(af[i], bf[j], acc[i][j], 0, 0, 0);
    }
    __syncthreads();
  }

#pragma unroll
  for (int i = 0; i < 2; ++i) {
#pragma unroll
    for (int jj = 0; jj < 4; ++jj) {
      int r = mt * 64 + warow + i * 16 + (lane >> 4) * 4 + jj;
      if (r < n_e) {
        int tk = tok_list[row0 + r];
        float gt = gate_lst[row0 + r];
        int sl = slot_lst[row0 + r];
        float* yrow = yslots + ((size_t)sl * T_TOK + tk) * DIM;
#pragma unroll
        for (int j = 0; j < 4; ++j) {
          int d = nt * 128 + wacol + j * 16 + (lane & 15);
          yrow[d] = gt * acc[i][j][jj];
        }
      }
    }
  }
}

// ---------------- combine slots ----------------
__global__ void combine(const float* __restrict__ y, float* __restrict__ out) {
  int i = blockIdx.x * blockDim.x + threadIdx.x;
  int stride = gridDim.x * blockDim.x;
  const float4* y0 = reinterpret_cast<const float4*>(y);
  const float4* y1 = reinterpret_cast<const float4*>(y + (size_t)T_TOK * DIM);
  float4* o = reinterpret_cast<float4*>(out);
  for (; i < T_TOK * DIM / 4; i += stride) {
    float4 a = y0[i], b = y1[i];
    float4 r;
    r.x = a.x + b.x; r.y = a.y + b.y; r.z = a.z + b.z; r.w = a.w + b.w;
    o[i] = r;
  }
}

extern "C" void kernel_launch(void* const* d_in, const int* in_sizes, int n_in,
                              void* d_out, int out_size, void* d_ws, size_t ws_size,
                              hipStream_t stream) {
  const float* x = (const float*)d_in[0];
  const float* wr = (const float*)d_in[1];
  const float* wg = (const float*)d_in[2];
  const float* wu = (const float*)d_in[3];
  const float* wd = (const float*)d_in[4];
  float* out = (float*)d_out;

  char* ws = (char*)d_ws;
  size_t off = 0;
  auto alloc = [&](size_t bytes) {
    char* p = ws + off;
    off += (bytes + 255) & ~(size_t)255;
    return p;
  };
  unsigned short* xb   = (unsigned short*)alloc((size_t)T_TOK * DIM * 2);
  unsigned short* wgb  = (unsigned short*)alloc((size_t)NE * FFN * DIM * 2);
  unsigned short* wub  = (unsigned short*)alloc((size_t)NE * FFN * DIM * 2);
  unsigned short* wdb  = (unsigned short*)alloc((size_t)NE * DIM * FFN * 2);
  unsigned short* hbuf = (unsigned short*)alloc((size_t)T_TOK * 2 * FFN * 2);
  float* yslots        = (float*)alloc((size_t)2 * T_TOK * DIM * 4);
  int* top_i     = (int*)alloc(T_TOK * 2 * 4);
  float* top_g   = (float*)alloc(T_TOK * 2 * 4);
  int* tok_list  = (int*)alloc(T_TOK * 2 * 4);
  float* gate_lst = (float*)alloc(T_TOK * 2 * 4);
  int* slot_lst  = (int*)alloc(T_TOK * 2 * 4);
  int* offs      = (int*)alloc(64);
  int* cursor    = (int*)alloc(64);
  if (off > ws_size) return;

  cvt_bulk<<<6656, 256, 0, stream>>>(x, wg, wu, wd, xb, wgb, wub, wdb);
  router_topk<<<T_TOK / 4, 256, 0, stream>>>(x, wr, top_i, top_g);
  count_offsets<<<1, 256, 0, stream>>>(top_i, offs, cursor);
  scatter_tokens<<<(T_TOK + 255) / 256, 256, 0, stream>>>(top_i, top_g, cursor, tok_list,
                                                          gate_lst, slot_lst);
  gateup_gemm<<<dim3(FFN / 64, 32, NE), 256, 0, stream>>>(xb, wgb, wub, tok_list, offs, hbuf);
  down_gemm<<<dim3(DIM / 128, 32, NE), 256, 0, stream>>>(hbuf, wdb, tok_list, gate_lst,
                                                         slot_lst, offs, yslots);
  combine<<<2048, 256, 0, stream>>>(yslots, out);
}